// Round 2
// baseline (2069.065 us; speedup 1.0000x reference)
//
#include <hip/hip_runtime.h>

#define HID   2048
#define INTER 8192
#define NEXP  8
#define NTOK  16384   // 4 * 4096

typedef unsigned short u16;
typedef __bf16 bf16x8 __attribute__((ext_vector_type(8)));
typedef float  floatx4 __attribute__((ext_vector_type(4)));
typedef u16    u16x4   __attribute__((ext_vector_type(4)));

typedef __attribute__((address_space(3))) void       lds_void_t;
typedef const __attribute__((address_space(1))) void gbl_void_t;

__device__ __forceinline__ u16 f2bf(float f) {
    union { float f; unsigned u; } v; v.f = f;
    unsigned r = v.u + 0x7fffu + ((v.u >> 16) & 1u);  // round-to-nearest-even
    return (u16)(r >> 16);
}

__device__ __forceinline__ void load_lds16(const void* g, void* l) {
    __builtin_amdgcn_global_load_lds((gbl_void_t*)g, (lds_void_t*)l, 16, 0, 0);
}

#define VM_WAIT(n) asm volatile("s_waitcnt vmcnt(" #n ")" ::: "memory")
#define SCHED_FENCE() __builtin_amdgcn_sched_barrier(0)

// ---------------------------------------------------------------------------
// Kernel 1: per-token gate logits (fp32) -> top-2 sum scale; write x_bf16 and
// xs_bf16 = x * scale. One wave per token, 4 tokens per block.
// ---------------------------------------------------------------------------
__global__ __launch_bounds__(256) void prep_tokens(
    const float* __restrict__ x, const float* __restrict__ gate,
    u16* __restrict__ xb, u16* __restrict__ xsb)
{
    int token = blockIdx.x * 4 + (threadIdx.x >> 6);
    int lane  = threadIdx.x & 63;
    const float* xr = x + (size_t)token * HID;

    float acc[NEXP];
#pragma unroll
    for (int e = 0; e < NEXP; ++e) acc[e] = 0.f;
#pragma unroll
    for (int c = 0; c < 8; ++c) {
        int kbase = lane * 32 + c * 4;
        float4 v = *(const float4*)(xr + kbase);
        float vv[4] = {v.x, v.y, v.z, v.w};
#pragma unroll
        for (int q = 0; q < 4; ++q) {
            const float* g = gate + (size_t)(kbase + q) * NEXP;
            float4 g0 = *(const float4*)(g);
            float4 g1 = *(const float4*)(g + 4);
            acc[0] += vv[q] * g0.x; acc[1] += vv[q] * g0.y;
            acc[2] += vv[q] * g0.z; acc[3] += vv[q] * g0.w;
            acc[4] += vv[q] * g1.x; acc[5] += vv[q] * g1.y;
            acc[6] += vv[q] * g1.z; acc[7] += vv[q] * g1.w;
        }
    }
#pragma unroll
    for (int off = 32; off >= 1; off >>= 1) {
#pragma unroll
        for (int e = 0; e < NEXP; ++e) acc[e] += __shfl_xor(acc[e], off, 64);
    }
    float m1 = acc[0], m2 = -3.4e38f;
#pragma unroll
    for (int e = 1; e < NEXP; ++e) {
        float v = acc[e];
        if (v > m1) { m2 = m1; m1 = v; } else if (v > m2) { m2 = v; }
    }
    float scale = m1 + m2;

    u16* xo  = xb  + (size_t)token * HID;
    u16* xso = xsb + (size_t)token * HID;
#pragma unroll
    for (int c = 0; c < 8; ++c) {
        int idx = (c * 64 + lane) * 4;
        float4 v = *(const float4*)(xr + idx);
        u16x4 b  = { f2bf(v.x), f2bf(v.y), f2bf(v.z), f2bf(v.w) };
        u16x4 bs = { f2bf(v.x * scale), f2bf(v.y * scale),
                     f2bf(v.z * scale), f2bf(v.w * scale) };
        *(u16x4*)(xo  + idx) = b;
        *(u16x4*)(xso + idx) = bs;
    }
}

// ---------------------------------------------------------------------------
// Kernel 2: transpose + cast  in[K][N] fp32 -> out[N][K] bf16
// ---------------------------------------------------------------------------
__global__ __launch_bounds__(256) void transpose_cast(
    const float* __restrict__ in, u16* __restrict__ out, int K, int N)
{
    __shared__ float t[32][33];
    int tx = threadIdx.x & 31;
    int ty = threadIdx.x >> 5;     // 0..7
    int k0 = blockIdx.y * 32, n0 = blockIdx.x * 32;
#pragma unroll
    for (int r = 0; r < 4; ++r)
        t[ty + r * 8][tx] = in[(size_t)(k0 + ty + r * 8) * N + n0 + tx];
    __syncthreads();
#pragma unroll
    for (int r = 0; r < 4; ++r)
        out[(size_t)(n0 + ty + r * 8) * K + k0 + tx] = f2bf(t[tx][ty + r * 8]);
}

// ---------------------------------------------------------------------------
// GEMM core v2b: BM=BN=256, BK=32, 512 threads (8 waves, 2M x 4N), per-wave
// output 128x64 (acc[8][4] of 16x16 frags). 4-deep LDS ring buffer (128 KiB):
// iteration t computes tile t from buf[t&3] while issuing tile t+3's
// global_load_lds into buf[(t+3)&3]. One raw s_barrier + counted
// s_waitcnt vmcnt(8) per K-tile (never drained to 0 in the main loop;
// epilogue peel drains 8 -> 4 -> 0).   [T1+T2+T3+T4+T5 per the catalog]
//
// HARDENING vs v2 (round-0 container failure): raw s_barrier is NOT an LLVM
// memory fence, so (a) next-phase ds_reads could legally hoist above it and
// (b) MFMAs + their lgkmcnt waits could sink below it (rule #18 analog).
// Fix: sched_barrier(0) at every sync-point boundary — end of the MFMA
// cluster, and immediately after each s_barrier. Within-phase scheduling
// freedom is preserved.
//
// LDS layout per tile: row-major [256][32] bf16 (64 B/row = 4 x 16B chunks).
// Chunk swizzle: LDS slot s of row r holds global chunk s ^ ((r>>1)&3).
// With the wave-linear global_load_lds lane mapping (row = base + lane>>2,
// slot = lane&3) the source swizzle reduces to the lane-only constant
// q = (lane&3) ^ ((lane>>3)&3); the read slot reduces to
// quad ^ ((l16>>1)&3). Read banks: 2-way aliasing only (free).
// ---------------------------------------------------------------------------
#define GM 256
#define GN 256
#define GK 32
#define NBUF 4
#define TELEM (256 * GK)   // 8192 u16 per operand tile

__device__ __forceinline__ void compute_tile(
    const u16* Asb, const u16* Bsb, int aoff, int boff, int so,
    floatx4 acc[8][4])
{
    bf16x8 af[8], bfr[4];
#pragma unroll
    for (int i = 0; i < 8; ++i)
        af[i] = *(const bf16x8*)(Asb + aoff + i * (16 * GK) + so);
#pragma unroll
    for (int j = 0; j < 4; ++j)
        bfr[j] = *(const bf16x8*)(Bsb + boff + j * (16 * GK) + so);
    __builtin_amdgcn_s_setprio(1);
#pragma unroll
    for (int i = 0; i < 8; ++i)
#pragma unroll
        for (int j = 0; j < 4; ++j)
            acc[i][j] = __builtin_amdgcn_mfma_f32_16x16x32_bf16(
                af[i], bfr[j], acc[i][j], 0, 0, 0);
    __builtin_amdgcn_s_setprio(0);
    SCHED_FENCE();   // MFMAs + lgkm waits may not sink past the coming sync
}

// GEMM1: h = bf16(relu(x @ up)^2), h[NTOK][INTER]. Both operands have
// K-stride HID (A = x_bf16 [NTOK][HID], B = up^T [INTER][HID]).
__global__ __launch_bounds__(512, 2) void gemm_up(
    const u16* __restrict__ A,   // x_bf16 [NTOK][HID]
    const u16* __restrict__ Bt,  // up^T   [INTER][HID]
    u16* __restrict__ H)         // out    [NTOK][INTER]
{
    __shared__ u16 As[NBUF][TELEM];
    __shared__ u16 Bs[NBUF][TELEM];

    int tid = threadIdx.x;
    int w = tid >> 6, lane = tid & 63;
    int wm = w >> 2, wn = w & 3;
    int quad = lane >> 4, l16 = lane & 15;

    // XCD chunk swizzle: nwg = 32*64 = 2048, 2048 % 8 == 0 -> simple form.
    int lid = blockIdx.y * 32 + blockIdx.x;
    int swz = (lid & 7) * (2048 / 8) + (lid >> 3);
    int bx = swz & 31, by = swz >> 5;
    int m0 = by * GM, n0 = bx * GN;

    // staging: per thread 2 A-loads + 2 B-loads of 16 B
    int q  = (lane & 3) ^ ((lane >> 3) & 3);        // pre-swizzled src chunk
    int rp = w * 16 + (lane >> 2);                  // row 0..127 (half 0)
    int offA0 = rp * HID + q * 8;                   // element offset in panel
    int offA1 = offA0 + 128 * HID;                  // half 1
    int lds0 = w * (16 * GK);                       // wave-uniform LDS base
    int lds1 = lds0 + 128 * GK;
    const u16* Ab = A  + (size_t)m0 * HID;
    const u16* Bb = Bt + (size_t)n0 * HID;

    int so   = l16 * GK + (quad ^ ((l16 >> 1) & 3)) * 8;
    int aoff = wm * (128 * GK), boff = wn * (64 * GK);

    floatx4 acc[8][4];
#pragma unroll
    for (int i = 0; i < 8; ++i)
#pragma unroll
        for (int j = 0; j < 4; ++j) acc[i][j] = (floatx4){0.f, 0.f, 0.f, 0.f};

#define UP_ISSUE(it) {                                                        \
        int b_ = (it) & 3; int kk_ = (it) * GK;                               \
        load_lds16(Ab + offA0 + kk_, &As[b_][lds0]);                          \
        load_lds16(Ab + offA1 + kk_, &As[b_][lds1]);                          \
        load_lds16(Bb + offA0 + kk_, &Bs[b_][lds0]);                          \
        load_lds16(Bb + offA1 + kk_, &Bs[b_][lds1]); }

    const int NT = HID / GK;  // 64
    UP_ISSUE(0) UP_ISSUE(1) UP_ISSUE(2)
    VM_WAIT(8);                         // tile 0 landed (own wave)
    __builtin_amdgcn_s_barrier();       // ... and everyone else's
    SCHED_FENCE();                      // ds_reads may not hoist above barrier

    for (int t = 0; t < NT - 3; ++t) {
        UP_ISSUE(t + 3)
        compute_tile(As[t & 3], Bs[t & 3], aoff, boff, so, acc);
        VM_WAIT(8);                     // tile t+1 landed; t+2,t+3 in flight
        __builtin_amdgcn_s_barrier();
        SCHED_FENCE();
    }
    compute_tile(As[(NT - 3) & 3], Bs[(NT - 3) & 3], aoff, boff, so, acc);
    VM_WAIT(4);
    __builtin_amdgcn_s_barrier();
    SCHED_FENCE();
    compute_tile(As[(NT - 2) & 3], Bs[(NT - 2) & 3], aoff, boff, so, acc);
    VM_WAIT(0);
    __builtin_amdgcn_s_barrier();
    SCHED_FENCE();
    compute_tile(As[(NT - 1) & 3], Bs[(NT - 1) & 3], aoff, boff, so, acc);
#undef UP_ISSUE

    int mrow = m0 + wm * 128;
    int ncol = n0 + wn * 64;
#pragma unroll
    for (int i = 0; i < 8; ++i) {
#pragma unroll
        for (int j = 0; j < 4; ++j) {
            int mbase = mrow + i * 16 + quad * 4;
            int n = ncol + j * 16 + l16;
#pragma unroll
            for (int r = 0; r < 4; ++r) {
                float v = acc[i][j][r];
                v = fmaxf(v, 0.f);
                v = v * v;
                H[(size_t)(mbase + r) * INTER + n] = f2bf(v);
            }
        }
    }
}

// GEMM2: y = h @ down^T (K=8192) + xs @ expert^T (K=2048), fp32 out.
// Phase 1 operands have K-stride INTER, phase 2 K-stride HID.
__global__ __launch_bounds__(512, 2) void gemm_down_moe(
    const u16* __restrict__ Hh,  // [NTOK][INTER]
    const u16* __restrict__ XS,  // [NTOK][HID]
    const u16* __restrict__ Dt,  // down^T   [HID][INTER]
    const u16* __restrict__ Et,  // expert^T [HID][HID]
    float* __restrict__ Y)       // [NTOK][HID]
{
    __shared__ u16 As[NBUF][TELEM];
    __shared__ u16 Bs[NBUF][TELEM];

    int tid = threadIdx.x;
    int w = tid >> 6, lane = tid & 63;
    int wm = w >> 2, wn = w & 3;
    int quad = lane >> 4, l16 = lane & 15;

    // XCD chunk swizzle: nwg = 8*64 = 512, 512 % 8 == 0.
    int lid = blockIdx.y * 8 + blockIdx.x;
    int swz = (lid & 7) * (512 / 8) + (lid >> 3);
    int bx = swz & 7, by = swz >> 3;
    int m0 = by * GM, n0 = bx * GN;

    int q  = (lane & 3) ^ ((lane >> 3) & 3);
    int rp = w * 16 + (lane >> 2);
    int offI0 = rp * INTER + q * 8, offI1 = offI0 + 128 * INTER;
    int offH0 = rp * HID   + q * 8, offH1 = offH0 + 128 * HID;
    int lds0 = w * (16 * GK);
    int lds1 = lds0 + 128 * GK;
    const u16* A1 = Hh + (size_t)m0 * INTER;
    const u16* B1 = Dt + (size_t)n0 * INTER;
    const u16* A2 = XS + (size_t)m0 * HID;
    const u16* B2 = Et + (size_t)n0 * HID;

    int so   = l16 * GK + (quad ^ ((l16 >> 1) & 3)) * 8;
    int aoff = wm * (128 * GK), boff = wn * (64 * GK);

    floatx4 acc[8][4];
#pragma unroll
    for (int i = 0; i < 8; ++i)
#pragma unroll
        for (int j = 0; j < 4; ++j) acc[i][j] = (floatx4){0.f, 0.f, 0.f, 0.f};

    const int KT1 = INTER / GK;          // 256
    const int NT  = KT1 + HID / GK;      // 320

#define DN_ISSUE(it) {                                                        \
        int b_ = (it) & 3;                                                    \
        if ((it) < KT1) {                                                     \
            int kk_ = (it) * GK;                                              \
            load_lds16(A1 + offI0 + kk_, &As[b_][lds0]);                      \
            load_lds16(A1 + offI1 + kk_, &As[b_][lds1]);                      \
            load_lds16(B1 + offI0 + kk_, &Bs[b_][lds0]);                      \
            load_lds16(B1 + offI1 + kk_, &Bs[b_][lds1]);                      \
        } else {                                                              \
            int kk_ = ((it) - KT1) * GK;                                      \
            load_lds16(A2 + offH0 + kk_, &As[b_][lds0]);                      \
            load_lds16(A2 + offH1 + kk_, &As[b_][lds1]);                      \
            load_lds16(B2 + offH0 + kk_, &Bs[b_][lds0]);                      \
            load_lds16(B2 + offH1 + kk_, &Bs[b_][lds1]); } }

    DN_ISSUE(0) DN_ISSUE(1) DN_ISSUE(2)
    VM_WAIT(8);
    __builtin_amdgcn_s_barrier();
    SCHED_FENCE();

    for (int t = 0; t < NT - 3; ++t) {
        DN_ISSUE(t + 3)
        compute_tile(As[t & 3], Bs[t & 3], aoff, boff, so, acc);
        VM_WAIT(8);
        __builtin_amdgcn_s_barrier();
        SCHED_FENCE();
    }
    compute_tile(As[(NT - 3) & 3], Bs[(NT - 3) & 3], aoff, boff, so, acc);
    VM_WAIT(4);
    __builtin_amdgcn_s_barrier();
    SCHED_FENCE();
    compute_tile(As[(NT - 2) & 3], Bs[(NT - 2) & 3], aoff, boff, so, acc);
    VM_WAIT(0);
    __builtin_amdgcn_s_barrier();
    SCHED_FENCE();
    compute_tile(As[(NT - 1) & 3], Bs[(NT - 1) & 3], aoff, boff, so, acc);
#undef DN_ISSUE

    int mrow = m0 + wm * 128;
    int ncol = n0 + wn * 64;
#pragma unroll
    for (int i = 0; i < 8; ++i) {
#pragma unroll
        for (int j = 0; j < 4; ++j) {
            int mbase = mrow + i * 16 + quad * 4;
            int n = ncol + j * 16 + l16;
#pragma unroll
            for (int r = 0; r < 4; ++r)
                Y[(size_t)(mbase + r) * HID + n] = acc[i][j][r];
        }
    }
}

// ---------------------------------------------------------------------------
// Kernel 5: LayerNorm in-place over d_out rows
// ---------------------------------------------------------------------------
__global__ __launch_bounds__(256) void ln_kernel(
    float* __restrict__ y, const float* __restrict__ gamma,
    const float* __restrict__ beta)
{
    int token = blockIdx.x;
    int t = threadIdx.x;
    float* yr = y + (size_t)token * HID;
    float4 v0 = ((const float4*)yr)[t];
    float4 v1 = ((const float4*)yr)[t + 256];
    float s  = v0.x + v0.y + v0.z + v0.w + v1.x + v1.y + v1.z + v1.w;
    float ss = v0.x*v0.x + v0.y*v0.y + v0.z*v0.z + v0.w*v0.w
             + v1.x*v1.x + v1.y*v1.y + v1.z*v1.z + v1.w*v1.w;
#pragma unroll
    for (int off = 32; off >= 1; off >>= 1) {
        s  += __shfl_xor(s,  off, 64);
        ss += __shfl_xor(ss, off, 64);
    }
    __shared__ float rs_[4], rss_[4];
    int w = t >> 6, lane = t & 63;
    if (lane == 0) { rs_[w] = s; rss_[w] = ss; }
    __syncthreads();
    s  = rs_[0] + rs_[1] + rs_[2] + rs_[3];
    ss = rss_[0] + rss_[1] + rss_[2] + rss_[3];
    float mu  = s * (1.f / HID);
    float var = ss * (1.f / HID) - mu * mu;
    float rstd = rsqrtf(var + 1e-5f);
    float4 g0 = ((const float4*)gamma)[t];
    float4 g1 = ((const float4*)gamma)[t + 256];
    float4 b0 = ((const float4*)beta)[t];
    float4 b1 = ((const float4*)beta)[t + 256];
    float4 o0, o1;
    o0.x = (v0.x - mu) * rstd * g0.x + b0.x;
    o0.y = (v0.y - mu) * rstd * g0.y + b0.y;
    o0.z = (v0.z - mu) * rstd * g0.z + b0.z;
    o0.w = (v0.w - mu) * rstd * g0.w + b0.w;
    o1.x = (v1.x - mu) * rstd * g1.x + b1.x;
    o1.y = (v1.y - mu) * rstd * g1.y + b1.y;
    o1.z = (v1.z - mu) * rstd * g1.z + b1.z;
    o1.w = (v1.w - mu) * rstd * g1.w + b1.w;
    ((float4*)yr)[t]       = o0;
    ((float4*)yr)[t + 256] = o1;
}

// ---------------------------------------------------------------------------
extern "C" void kernel_launch(void* const* d_in, const int* in_sizes, int n_in,
                              void* d_out, int out_size, void* d_ws, size_t ws_size,
                              hipStream_t stream) {
    const float* x     = (const float*)d_in[0];
    const float* gate  = (const float*)d_in[1];
    const float* up    = (const float*)d_in[2];
    const float* down  = (const float*)d_in[3];
    const float* expw  = (const float*)d_in[4];
    const float* gamma = (const float*)d_in[5];
    const float* beta  = (const float*)d_in[6];
    float* out = (float*)d_out;

    // workspace layout (elements of u16)
    u16* ws  = (u16*)d_ws;
    u16* xb  = ws;                          // 33,554,432  x_bf16
    u16* xsb = xb  + (size_t)NTOK * HID;    // 33,554,432  x*scale bf16
    u16* upT = xsb + (size_t)NTOK * HID;    // 16,777,216  up^T
    u16* dT  = upT + (size_t)INTER * HID;   // 16,777,216  down^T
    u16* eT  = dT  + (size_t)INTER * HID;   //  4,194,304  expert^T
    u16* h   = eT  + (size_t)HID * HID;     // 134,217,728 relu(up(x))^2

    prep_tokens<<<dim3(NTOK / 4), dim3(256), 0, stream>>>(x, gate, xb, xsb);
    transpose_cast<<<dim3(INTER / 32, HID / 32), dim3(256), 0, stream>>>(up, upT, HID, INTER);
    transpose_cast<<<dim3(HID / 32, INTER / 32), dim3(256), 0, stream>>>(down, dT, INTER, HID);
    transpose_cast<<<dim3(HID / 32, HID / 32), dim3(256), 0, stream>>>(expw, eT, HID, HID);
    gemm_up<<<dim3(INTER / GN, NTOK / GM), dim3(512), 0, stream>>>(xb, upT, h);
    gemm_down_moe<<<dim3(HID / GN, NTOK / GM), dim3(512), 0, stream>>>(h, xsb, dT, eT, out);
    ln_kernel<<<dim3(NTOK), dim3(256), 0, stream>>>(out, gamma, beta);
}

// Round 3
// 1808.292 us; speedup vs baseline: 1.1442x; 1.1442x over previous
//
#include <hip/hip_runtime.h>

#define HID   2048
#define INTER 8192
#define NEXP  8
#define NTOK  16384   // 4 * 4096

typedef unsigned short u16;
typedef __bf16 bf16x8 __attribute__((ext_vector_type(8)));
typedef float  floatx4 __attribute__((ext_vector_type(4)));
typedef u16    u16x4   __attribute__((ext_vector_type(4)));

typedef __attribute__((address_space(3))) void       lds_void_t;
typedef const __attribute__((address_space(1))) void gbl_void_t;

__device__ __forceinline__ u16 f2bf(float f) {
    union { float f; unsigned u; } v; v.f = f;
    unsigned r = v.u + 0x7fffu + ((v.u >> 16) & 1u);  // round-to-nearest-even
    return (u16)(r >> 16);
}

__device__ __forceinline__ void load_lds16(const void* g, void* l) {
    __builtin_amdgcn_global_load_lds((gbl_void_t*)g, (lds_void_t*)l, 16, 0, 0);
}

#define VM_WAIT(n)  asm volatile("s_waitcnt vmcnt(" #n ")" ::: "memory")
#define LGKM_WAIT0() asm volatile("s_waitcnt lgkmcnt(0)" ::: "memory")
#define SCHED_FENCE() __builtin_amdgcn_sched_barrier(0)

// ---------------------------------------------------------------------------
// Kernel 1: per-token gate logits (fp32) -> top-2 sum scale; write x_bf16 and
// xs_bf16 = x * scale. One wave per token, 4 tokens per block.
// ---------------------------------------------------------------------------
__global__ __launch_bounds__(256) void prep_tokens(
    const float* __restrict__ x, const float* __restrict__ gate,
    u16* __restrict__ xb, u16* __restrict__ xsb)
{
    int token = blockIdx.x * 4 + (threadIdx.x >> 6);
    int lane  = threadIdx.x & 63;
    const float* xr = x + (size_t)token * HID;

    float acc[NEXP];
#pragma unroll
    for (int e = 0; e < NEXP; ++e) acc[e] = 0.f;
#pragma unroll
    for (int c = 0; c < 8; ++c) {
        int kbase = lane * 32 + c * 4;
        float4 v = *(const float4*)(xr + kbase);
        float vv[4] = {v.x, v.y, v.z, v.w};
#pragma unroll
        for (int q = 0; q < 4; ++q) {
            const float* g = gate + (size_t)(kbase + q) * NEXP;
            float4 g0 = *(const float4*)(g);
            float4 g1 = *(const float4*)(g + 4);
            acc[0] += vv[q] * g0.x; acc[1] += vv[q] * g0.y;
            acc[2] += vv[q] * g0.z; acc[3] += vv[q] * g0.w;
            acc[4] += vv[q] * g1.x; acc[5] += vv[q] * g1.y;
            acc[6] += vv[q] * g1.z; acc[7] += vv[q] * g1.w;
        }
    }
#pragma unroll
    for (int off = 32; off >= 1; off >>= 1) {
#pragma unroll
        for (int e = 0; e < NEXP; ++e) acc[e] += __shfl_xor(acc[e], off, 64);
    }
    float m1 = acc[0], m2 = -3.4e38f;
#pragma unroll
    for (int e = 1; e < NEXP; ++e) {
        float v = acc[e];
        if (v > m1) { m2 = m1; m1 = v; } else if (v > m2) { m2 = v; }
    }
    float scale = m1 + m2;

    u16* xo  = xb  + (size_t)token * HID;
    u16* xso = xsb + (size_t)token * HID;
#pragma unroll
    for (int c = 0; c < 8; ++c) {
        int idx = (c * 64 + lane) * 4;
        float4 v = *(const float4*)(xr + idx);
        u16x4 b  = { f2bf(v.x), f2bf(v.y), f2bf(v.z), f2bf(v.w) };
        u16x4 bs = { f2bf(v.x * scale), f2bf(v.y * scale),
                     f2bf(v.z * scale), f2bf(v.w * scale) };
        *(u16x4*)(xo  + idx) = b;
        *(u16x4*)(xso + idx) = bs;
    }
}

// ---------------------------------------------------------------------------
// Kernel 2: transpose + cast  in[K][N] fp32 -> out[N][K] bf16
// ---------------------------------------------------------------------------
__global__ __launch_bounds__(256) void transpose_cast(
    const float* __restrict__ in, u16* __restrict__ out, int K, int N)
{
    __shared__ float t[32][33];
    int tx = threadIdx.x & 31;
    int ty = threadIdx.x >> 5;     // 0..7
    int k0 = blockIdx.y * 32, n0 = blockIdx.x * 32;
#pragma unroll
    for (int r = 0; r < 4; ++r)
        t[ty + r * 8][tx] = in[(size_t)(k0 + ty + r * 8) * N + n0 + tx];
    __syncthreads();
#pragma unroll
    for (int r = 0; r < 4; ++r)
        out[(size_t)(n0 + ty + r * 8) * K + k0 + tx] = f2bf(t[tx][ty + r * 8]);
}

// ---------------------------------------------------------------------------
// GEMM core v3: 256x256 tile, BK=32, 512 threads (8 waves 2Mx4N), 4-deep LDS
// ring (128 KiB), counted vmcnt(8) pipeline -- PLUS register double-buffering
// of MFMA fragments: while computing tile t's 32 MFMAs from register set CUR,
// each wave ds_reads tile t+1's 12 fragments into set NXT (tile t+1's DMA
// landed at end of iter t-1). The ds_read latency hides under own-wave MFMA
// (round-2 failure mode: reads exposed because all waves were phase-locked).
//
// Sync invariants per iter t:
//   ISSUE(t+4) overwrites slot t&3; frags(t) reads from that slot were
//   drained by the explicit lgkmcnt(0) BEFORE the end-of-iter-(t-1) barrier
//   (all waves), and the DMA write lands >=hundreds of cycles after issue.
//   VM_WAIT(8) at end of iter t => tile t+2 complete before iter t+1 reads
//   frags(t+2). Epilogue peels waits 8 -> 4 -> 0.
// ---------------------------------------------------------------------------
#define GM 256
#define GN 256
#define GK 32
#define NBUF 4
#define TELEM (256 * GK)   // 8192 u16 per operand tile

__device__ __forceinline__ void read_frags_v(
    const u16* Asb, const u16* Bsb, int aoff, int boff, int so,
    bf16x8 af[8], bf16x8 bfr[4])
{
#pragma unroll
    for (int i = 0; i < 8; ++i)
        af[i] = *(const bf16x8*)(Asb + aoff + i * (16 * GK) + so);
#pragma unroll
    for (int j = 0; j < 4; ++j)
        bfr[j] = *(const bf16x8*)(Bsb + boff + j * (16 * GK) + so);
}

__device__ __forceinline__ void mfma_cluster(
    const bf16x8 af[8], const bf16x8 bfr[4], floatx4 acc[8][4])
{
    __builtin_amdgcn_s_setprio(1);
#pragma unroll
    for (int i = 0; i < 8; ++i)
#pragma unroll
        for (int j = 0; j < 4; ++j)
            acc[i][j] = __builtin_amdgcn_mfma_f32_16x16x32_bf16(
                af[i], bfr[j], acc[i][j], 0, 0, 0);
    __builtin_amdgcn_s_setprio(0);
}

// One pipeline step: compute tile t from CUR regs, prefetch frags(t+1) into
// NXT regs, issue DMA for tile t+4 (if DOI), drain lgkm, counted vmcnt, bar.
#define GEMM_STEP(ISSUE_MACRO, t_, CA, CB, NA, NB, WAITN, DOI)                \
    {                                                                         \
        if (DOI) ISSUE_MACRO((t_) + 4);                                       \
        read_frags_v(As[((t_) + 1) & 3], Bs[((t_) + 1) & 3], aoff, boff, so,  \
                     NA, NB);                                                 \
        mfma_cluster(CA, CB, acc);                                            \
        SCHED_FENCE();                                                        \
        LGKM_WAIT0();                                                         \
        VM_WAIT(WAITN);                                                       \
        __builtin_amdgcn_s_barrier();                                         \
        SCHED_FENCE();                                                        \
    }

// GEMM1: h = bf16(relu(x @ up)^2), h[NTOK][INTER]. Both operands have
// K-stride HID (A = x_bf16 [NTOK][HID], B = up^T [INTER][HID]).
__global__ __launch_bounds__(512, 2) void gemm_up(
    const u16* __restrict__ A,   // x_bf16 [NTOK][HID]
    const u16* __restrict__ Bt,  // up^T   [INTER][HID]
    u16* __restrict__ H)         // out    [NTOK][INTER]
{
    __shared__ u16 As[NBUF][TELEM];
    __shared__ u16 Bs[NBUF][TELEM];

    int tid = threadIdx.x;
    int w = tid >> 6, lane = tid & 63;
    int wm = w >> 2, wn = w & 3;
    int quad = lane >> 4, l16 = lane & 15;

    // XCD chunk swizzle: nwg = 32*64 = 2048, 2048 % 8 == 0 -> simple form.
    int lid = blockIdx.y * 32 + blockIdx.x;
    int swz = (lid & 7) * (2048 / 8) + (lid >> 3);
    int bx = swz & 31, by = swz >> 5;
    int m0 = by * GM, n0 = bx * GN;

    // staging: per thread 2 A-loads + 2 B-loads of 16 B
    int q  = (lane & 3) ^ ((lane >> 3) & 3);        // pre-swizzled src chunk
    int rp = w * 16 + (lane >> 2);                  // row 0..127 (half 0)
    int offA0 = rp * HID + q * 8;                   // element offset in panel
    int offA1 = offA0 + 128 * HID;                  // half 1
    int lds0 = w * (16 * GK);                       // wave-uniform LDS base
    int lds1 = lds0 + 128 * GK;
    const u16* Ab = A  + (size_t)m0 * HID;
    const u16* Bb = Bt + (size_t)n0 * HID;

    int so   = l16 * GK + (quad ^ ((l16 >> 1) & 3)) * 8;
    int aoff = wm * (128 * GK), boff = wn * (64 * GK);

    floatx4 acc[8][4];
#pragma unroll
    for (int i = 0; i < 8; ++i)
#pragma unroll
        for (int j = 0; j < 4; ++j) acc[i][j] = (floatx4){0.f, 0.f, 0.f, 0.f};

#define UP_ISSUE(it) {                                                        \
        int b_ = (it) & 3; int kk_ = (it) * GK;                               \
        load_lds16(Ab + offA0 + kk_, &As[b_][lds0]);                          \
        load_lds16(Ab + offA1 + kk_, &As[b_][lds1]);                          \
        load_lds16(Bb + offA0 + kk_, &Bs[b_][lds0]);                          \
        load_lds16(Bb + offA1 + kk_, &Bs[b_][lds1]); }

    const int NT = HID / GK;  // 64
    bf16x8 afA[8], bfA[4], afB[8], bfB[4];

    // prologue: 4 tiles in flight; frags(0) into set A
    UP_ISSUE(0) UP_ISSUE(1) UP_ISSUE(2) UP_ISSUE(3)
    VM_WAIT(8);                         // tiles 0,1 landed (own wave)
    __builtin_amdgcn_s_barrier();       // ... and everyone else's
    SCHED_FENCE();
    read_frags_v(As[0], Bs[0], aoff, boff, so, afA, bfA);
    LGKM_WAIT0();                       // slot 0 reads done before ISSUE(4)
    __builtin_amdgcn_s_barrier();
    SCHED_FENCE();

    for (int t = 0; t < NT - 4; t += 2) {
        GEMM_STEP(UP_ISSUE, t,     afA, bfA, afB, bfB, 8, 1)
        GEMM_STEP(UP_ISSUE, t + 1, afB, bfB, afA, bfA, 8, 1)
    }
    GEMM_STEP(UP_ISSUE, NT - 4, afA, bfA, afB, bfB, 4, 0)
    GEMM_STEP(UP_ISSUE, NT - 3, afB, bfB, afA, bfA, 0, 0)
    // last two tiles: all DMA done, no slot reuse -> no barriers needed
    read_frags_v(As[(NT - 1) & 3], Bs[(NT - 1) & 3], aoff, boff, so, afB, bfB);
    mfma_cluster(afA, bfA, acc);
    mfma_cluster(afB, bfB, acc);
#undef UP_ISSUE

    int mrow = m0 + wm * 128;
    int ncol = n0 + wn * 64;
#pragma unroll
    for (int i = 0; i < 8; ++i) {
#pragma unroll
        for (int j = 0; j < 4; ++j) {
            int mbase = mrow + i * 16 + quad * 4;
            int n = ncol + j * 16 + l16;
#pragma unroll
            for (int r = 0; r < 4; ++r) {
                float v = acc[i][j][r];
                v = fmaxf(v, 0.f);
                v = v * v;
                H[(size_t)(mbase + r) * INTER + n] = f2bf(v);
            }
        }
    }
}

// GEMM2: y = h @ down^T (K=8192) + xs @ expert^T (K=2048), fp32 out.
// Phase 1 operands have K-stride INTER, phase 2 K-stride HID.
__global__ __launch_bounds__(512, 2) void gemm_down_moe(
    const u16* __restrict__ Hh,  // [NTOK][INTER]
    const u16* __restrict__ XS,  // [NTOK][HID]
    const u16* __restrict__ Dt,  // down^T   [HID][INTER]
    const u16* __restrict__ Et,  // expert^T [HID][HID]
    float* __restrict__ Y)       // [NTOK][HID]
{
    __shared__ u16 As[NBUF][TELEM];
    __shared__ u16 Bs[NBUF][TELEM];

    int tid = threadIdx.x;
    int w = tid >> 6, lane = tid & 63;
    int wm = w >> 2, wn = w & 3;
    int quad = lane >> 4, l16 = lane & 15;

    // XCD chunk swizzle: nwg = 8*64 = 512, 512 % 8 == 0.
    int lid = blockIdx.y * 8 + blockIdx.x;
    int swz = (lid & 7) * (512 / 8) + (lid >> 3);
    int bx = swz & 7, by = swz >> 3;
    int m0 = by * GM, n0 = bx * GN;

    int q  = (lane & 3) ^ ((lane >> 3) & 3);
    int rp = w * 16 + (lane >> 2);
    int offI0 = rp * INTER + q * 8, offI1 = offI0 + 128 * INTER;
    int offH0 = rp * HID   + q * 8, offH1 = offH0 + 128 * HID;
    int lds0 = w * (16 * GK);
    int lds1 = lds0 + 128 * GK;
    const u16* A1 = Hh + (size_t)m0 * INTER;
    const u16* B1 = Dt + (size_t)n0 * INTER;
    const u16* A2 = XS + (size_t)m0 * HID;
    const u16* B2 = Et + (size_t)n0 * HID;

    int so   = l16 * GK + (quad ^ ((l16 >> 1) & 3)) * 8;
    int aoff = wm * (128 * GK), boff = wn * (64 * GK);

    floatx4 acc[8][4];
#pragma unroll
    for (int i = 0; i < 8; ++i)
#pragma unroll
        for (int j = 0; j < 4; ++j) acc[i][j] = (floatx4){0.f, 0.f, 0.f, 0.f};

    const int KT1 = INTER / GK;          // 256
    const int NT  = KT1 + HID / GK;      // 320

#define DN_ISSUE(it) {                                                        \
        int b_ = (it) & 3;                                                    \
        if ((it) < KT1) {                                                     \
            int kk_ = (it) * GK;                                              \
            load_lds16(A1 + offI0 + kk_, &As[b_][lds0]);                      \
            load_lds16(A1 + offI1 + kk_, &As[b_][lds1]);                      \
            load_lds16(B1 + offI0 + kk_, &Bs[b_][lds0]);                      \
            load_lds16(B1 + offI1 + kk_, &Bs[b_][lds1]);                      \
        } else {                                                              \
            int kk_ = ((it) - KT1) * GK;                                      \
            load_lds16(A2 + offH0 + kk_, &As[b_][lds0]);                      \
            load_lds16(A2 + offH1 + kk_, &As[b_][lds1]);                      \
            load_lds16(B2 + offH0 + kk_, &Bs[b_][lds0]);                      \
            load_lds16(B2 + offH1 + kk_, &Bs[b_][lds1]); } }

    bf16x8 afA[8], bfA[4], afB[8], bfB[4];

    DN_ISSUE(0) DN_ISSUE(1) DN_ISSUE(2) DN_ISSUE(3)
    VM_WAIT(8);
    __builtin_amdgcn_s_barrier();
    SCHED_FENCE();
    read_frags_v(As[0], Bs[0], aoff, boff, so, afA, bfA);
    LGKM_WAIT0();
    __builtin_amdgcn_s_barrier();
    SCHED_FENCE();

    for (int t = 0; t < NT - 4; t += 2) {
        GEMM_STEP(DN_ISSUE, t,     afA, bfA, afB, bfB, 8, 1)
        GEMM_STEP(DN_ISSUE, t + 1, afB, bfB, afA, bfA, 8, 1)
    }
    GEMM_STEP(DN_ISSUE, NT - 4, afA, bfA, afB, bfB, 4, 0)
    GEMM_STEP(DN_ISSUE, NT - 3, afB, bfB, afA, bfA, 0, 0)
    read_frags_v(As[(NT - 1) & 3], Bs[(NT - 1) & 3], aoff, boff, so, afB, bfB);
    mfma_cluster(afA, bfA, acc);
    mfma_cluster(afB, bfB, acc);
#undef DN_ISSUE

    int mrow = m0 + wm * 128;
    int ncol = n0 + wn * 64;
#pragma unroll
    for (int i = 0; i < 8; ++i) {
#pragma unroll
        for (int j = 0; j < 4; ++j) {
            int mbase = mrow + i * 16 + quad * 4;
            int n = ncol + j * 16 + l16;
#pragma unroll
            for (int r = 0; r < 4; ++r)
                Y[(size_t)(mbase + r) * HID + n] = acc[i][j][r];
        }
    }
}

// ---------------------------------------------------------------------------
// Kernel 5: LayerNorm in-place over d_out rows
// ---------------------------------------------------------------------------
__global__ __launch_bounds__(256) void ln_kernel(
    float* __restrict__ y, const float* __restrict__ gamma,
    const float* __restrict__ beta)
{
    int token = blockIdx.x;
    int t = threadIdx.x;
    float* yr = y + (size_t)token * HID;
    float4 v0 = ((const float4*)yr)[t];
    float4 v1 = ((const float4*)yr)[t + 256];
    float s  = v0.x + v0.y + v0.z + v0.w + v1.x + v1.y + v1.z + v1.w;
    float ss = v0.x*v0.x + v0.y*v0.y + v0.z*v0.z + v0.w*v0.w
             + v1.x*v1.x + v1.y*v1.y + v1.z*v1.z + v1.w*v1.w;
#pragma unroll
    for (int off = 32; off >= 1; off >>= 1) {
        s  += __shfl_xor(s,  off, 64);
        ss += __shfl_xor(ss, off, 64);
    }
    __shared__ float rs_[4], rss_[4];
    int w = t >> 6, lane = t & 63;
    if (lane == 0) { rs_[w] = s; rss_[w] = ss; }
    __syncthreads();
    s  = rs_[0] + rs_[1] + rs_[2] + rs_[3];
    ss = rss_[0] + rss_[1] + rss_[2] + rss_[3];
    float mu  = s * (1.f / HID);
    float var = ss * (1.f / HID) - mu * mu;
    float rstd = rsqrtf(var + 1e-5f);
    float4 g0 = ((const float4*)gamma)[t];
    float4 g1 = ((const float4*)gamma)[t + 256];
    float4 b0 = ((const float4*)beta)[t];
    float4 b1 = ((const float4*)beta)[t + 256];
    float4 o0, o1;
    o0.x = (v0.x - mu) * rstd * g0.x + b0.x;
    o0.y = (v0.y - mu) * rstd * g0.y + b0.y;
    o0.z = (v0.z - mu) * rstd * g0.z + b0.z;
    o0.w = (v0.w - mu) * rstd * g0.w + b0.w;
    o1.x = (v1.x - mu) * rstd * g1.x + b1.x;
    o1.y = (v1.y - mu) * rstd * g1.y + b1.y;
    o1.z = (v1.z - mu) * rstd * g1.z + b1.z;
    o1.w = (v1.w - mu) * rstd * g1.w + b1.w;
    ((float4*)yr)[t]       = o0;
    ((float4*)yr)[t + 256] = o1;
}

// ---------------------------------------------------------------------------
extern "C" void kernel_launch(void* const* d_in, const int* in_sizes, int n_in,
                              void* d_out, int out_size, void* d_ws, size_t ws_size,
                              hipStream_t stream) {
    const float* x     = (const float*)d_in[0];
    const float* gate  = (const float*)d_in[1];
    const float* up    = (const float*)d_in[2];
    const float* down  = (const float*)d_in[3];
    const float* expw  = (const float*)d_in[4];
    const float* gamma = (const float*)d_in[5];
    const float* beta  = (const float*)d_in[6];
    float* out = (float*)d_out;

    // workspace layout (elements of u16)
    u16* ws  = (u16*)d_ws;
    u16* xb  = ws;                          // 33,554,432  x_bf16
    u16* xsb = xb  + (size_t)NTOK * HID;    // 33,554,432  x*scale bf16
    u16* upT = xsb + (size_t)NTOK * HID;    // 16,777,216  up^T
    u16* dT  = upT + (size_t)INTER * HID;   // 16,777,216  down^T
    u16* eT  = dT  + (size_t)INTER * HID;   //  4,194,304  expert^T
    u16* h   = eT  + (size_t)HID * HID;     // 134,217,728 relu(up(x))^2

    prep_tokens<<<dim3(NTOK / 4), dim3(256), 0, stream>>>(x, gate, xb, xsb);
    transpose_cast<<<dim3(INTER / 32, HID / 32), dim3(256), 0, stream>>>(up, upT, HID, INTER);
    transpose_cast<<<dim3(HID / 32, INTER / 32), dim3(256), 0, stream>>>(down, dT, INTER, HID);
    transpose_cast<<<dim3(HID / 32, HID / 32), dim3(256), 0, stream>>>(expw, eT, HID, HID);
    gemm_up<<<dim3(INTER / GN, NTOK / GM), dim3(512), 0, stream>>>(xb, upT, h);
    gemm_down_moe<<<dim3(HID / GN, NTOK / GM), dim3(512), 0, stream>>>(h, xsb, dT, eT, out);
    ln_kernel<<<dim3(NTOK), dim3(256), 0, stream>>>(out, gamma, beta);
}